// Round 1
// baseline (2413.990 us; speedup 1.0000x reference)
//
#include <hip/hip_runtime.h>

#define MID 3
#define NVEC 32
#define ROW_F 96              // MID*NVEC floats per node/edge row
#define CHUNKS_PER_EDGE 24    // 96 floats / 4

// ---------------------------------------------------------------------------
// Kernel 1: per-edge weighted features scattered (atomically) into two node
// accumulators: acc_d[dst] += W*xe, acc_s[src] += W*xe.
// One thread per float4 chunk: t = e*24 + j, j = m*8 + v4.
// ---------------------------------------------------------------------------
__global__ __launch_bounds__(256) void edge_scatter_kernel(
    const float4* __restrict__ xe4,   // [E*24] float4 view of [E,3,32]
    const float4* __restrict__ W4,    // [E*8]  float4 view of [E,32]
    const int* __restrict__ xe_src,
    const int* __restrict__ xe_dst,
    float* __restrict__ acc_d,        // [N*96] segment_sum by dst
    float* __restrict__ acc_s,        // [N*96] segment_sum by src
    int n_chunks)
{
    int t = blockIdx.x * blockDim.x + threadIdx.x;
    if (t >= n_chunks) return;
    int e  = t / CHUNKS_PER_EDGE;
    int j  = t - e * CHUNKS_PER_EDGE;  // 0..23
    int m  = j >> 3;                    // 0..2
    int v4 = j & 7;                     // 0..7

    float4 x = xe4[t];                  // coalesced: chunk index == t
    float4 w = W4[e * 8 + v4];          // reused 3x across m, L1-resident

    float4 p;
    p.x = x.x * w.x; p.y = x.y * w.y; p.z = x.z * w.z; p.w = x.w * w.w;

    int d = xe_dst[e];
    int s = xe_src[e];
    int off = m * NVEC + v4 * 4;

    float* a1 = acc_d + (size_t)d * ROW_F + off;
    float* a2 = acc_s + (size_t)s * ROW_F + off;

    // HW global_atomic_add_f32 (coarse-grained device memory => safe)
    unsafeAtomicAdd(a1 + 0, p.x);
    unsafeAtomicAdd(a1 + 1, p.y);
    unsafeAtomicAdd(a1 + 2, p.z);
    unsafeAtomicAdd(a1 + 3, p.w);
    unsafeAtomicAdd(a2 + 0, p.x);
    unsafeAtomicAdd(a2 + 1, p.y);
    unsafeAtomicAdd(a2 + 2, p.z);
    unsafeAtomicAdd(a2 + 3, p.w);
}

// ---------------------------------------------------------------------------
// Kernel 2: per (node, m) row: out = acc_d_row @ A + acc_s_row @ B
// with A = 0.5*(M1+M2), B = 0.5*(M2-M1)  (xn = x1@A + x2@B algebraically
// equal to 0.5*((x1-x2)@M1 + (x1+x2)@M2)).
// 32 lanes per row; row values broadcast via shfl within the 32-lane group.
// NOTE: acc_d may alias out (ws-size fallback). Safe: each address is read
// only by the lane that later writes it; cross-lane data moves via shfl.
// ---------------------------------------------------------------------------
__global__ __launch_bounds__(256) void node_mix_kernel(
    const float* acc_d,               // [nRows*32]
    const float* acc_s,               // [nRows*32]
    const float* __restrict__ M1,     // [32,32]
    const float* __restrict__ M2,     // [32,32]
    float* out,                       // [nRows*32]
    int n_rows)
{
    __shared__ float As[NVEC * NVEC];
    __shared__ float Bs[NVEC * NVEC];
    for (int i = threadIdx.x; i < NVEC * NVEC; i += blockDim.x) {
        float m1 = M1[i], m2 = M2[i];
        As[i] = 0.5f * (m1 + m2);
        Bs[i] = 0.5f * (m2 - m1);
    }
    __syncthreads();

    int r = blockIdx.x * (blockDim.x >> 5) + (threadIdx.x >> 5);
    int w = threadIdx.x & 31;
    if (r >= n_rows) return;

    float a1 = acc_d[r * NVEC + w];
    float a2 = acc_s[r * NVEC + w];

    float acc = 0.f;
    #pragma unroll
    for (int v = 0; v < NVEC; ++v) {
        float b1 = __shfl(a1, v, 32);
        float b2 = __shfl(a2, v, 32);
        acc += b1 * As[v * NVEC + w] + b2 * Bs[v * NVEC + w];
    }
    out[r * NVEC + w] = acc;
}

extern "C" void kernel_launch(void* const* d_in, const int* in_sizes, int n_in,
                              void* d_out, int out_size, void* d_ws, size_t ws_size,
                              hipStream_t stream)
{
    const float* xe  = (const float*)d_in[0];   // [E,3,32]
    const float* W   = (const float*)d_in[1];   // [E,32]
    const float* M1  = (const float*)d_in[2];   // [32,32]
    const float* M2  = (const float*)d_in[3];   // [32,32]
    const int* xsrc  = (const int*)d_in[4];     // [E]
    const int* xdst  = (const int*)d_in[5];     // [E]

    const int E = in_sizes[4];
    const int N = out_size / ROW_F;             // nodes
    const size_t acc_bytes = (size_t)N * ROW_F * sizeof(float);

    float* acc_d;
    float* acc_s;
    if (ws_size >= 2 * acc_bytes) {
        acc_d = (float*)d_ws;
        acc_s = (float*)d_ws + (size_t)N * ROW_F;
        hipMemsetAsync(d_ws, 0, 2 * acc_bytes, stream);
    } else {
        // fallback: acc_d lives in d_out (in-place mix is race-free, see note)
        acc_d = (float*)d_out;
        acc_s = (float*)d_ws;
        hipMemsetAsync(d_out, 0, acc_bytes, stream);
        hipMemsetAsync(d_ws, 0, acc_bytes, stream);
    }

    const int n_chunks = E * CHUNKS_PER_EDGE;
    const int blk1 = (n_chunks + 255) / 256;
    edge_scatter_kernel<<<blk1, 256, 0, stream>>>(
        (const float4*)xe, (const float4*)W, xsrc, xdst, acc_d, acc_s, n_chunks);

    const int n_rows = N * MID;
    const int blk2 = (n_rows + 7) / 8;          // 8 rows per 256-thread block
    node_mix_kernel<<<blk2, 256, 0, stream>>>(
        acc_d, acc_s, M1, M2, (float*)d_out, n_rows);
}

// Round 2
// 1238.891 us; speedup vs baseline: 1.9485x; 1.9485x over previous
//
#include <hip/hip_runtime.h>

#define MID 3
#define NVEC 32
#define ROW_F 96   // MID*NVEC

// ---------------------------------------------------------------------------
// Device-built CSR over 2N segments: seg n   = edges with dst==n  (side 1)
//                                    seg N+n = edges with src==n  (side 2)
// ws layout (ints): counts[2N] | offsets[2N] | cursors[2N] | list[2E]
// ---------------------------------------------------------------------------

__global__ __launch_bounds__(256) void hist_kernel(
    const int* __restrict__ dst, const int* __restrict__ src,
    int* __restrict__ cnt, int E, int N)
{
    int t = blockIdx.x * blockDim.x + threadIdx.x;
    if (t >= E) return;
    atomicAdd(&cnt[dst[t]], 1);
    atomicAdd(&cnt[N + src[t]], 1);
}

// single-block exclusive scan over n=2N counts -> offsets (+ cursor copy)
__global__ __launch_bounds__(1024) void scan_kernel(
    const int* __restrict__ cnt, int* __restrict__ off,
    int* __restrict__ cur, int n)
{
    __shared__ int sdata[1024];
    int tid = threadIdx.x;
    int chunk = (n + 1023) >> 10;
    int begin = tid * chunk;
    int end = begin + chunk; if (end > n) end = n;
    int s = 0;
    for (int i = begin; i < end; ++i) s += cnt[i];
    sdata[tid] = s;
    __syncthreads();
    for (int o = 1; o < 1024; o <<= 1) {          // Hillis-Steele inclusive
        int v = (tid >= o) ? sdata[tid - o] : 0;
        __syncthreads();
        sdata[tid] += v;
        __syncthreads();
    }
    int run = sdata[tid] - s;                      // exclusive prefix
    for (int i = begin; i < end; ++i) {
        off[i] = run; cur[i] = run;
        run += cnt[i];
    }
}

__global__ __launch_bounds__(256) void scatter_kernel(
    const int* __restrict__ dst, const int* __restrict__ src,
    int* __restrict__ cur, int* __restrict__ list, int E, int N)
{
    int t = blockIdx.x * blockDim.x + threadIdx.x;
    if (t >= E) return;
    int p = atomicAdd(&cur[dst[t]], 1);
    list[p] = t;
    int q = atomicAdd(&cur[N + src[t]], 1);
    list[q] = t;
}

// ---------------------------------------------------------------------------
// One 64-lane wave per node. Lanes 0-31: dst-edge sum (x1). Lanes 32-63:
// src-edge sum (x2), concurrently. Then fused mix out = x1@A + x2@B with
// A=0.5*(M1+M2), B=0.5*(M2-M1) via cross-wave shfl; half 0 stores.
// ---------------------------------------------------------------------------
__global__ __launch_bounds__(256) void gather_mix_kernel(
    const float* __restrict__ xe,     // [E,3,32]
    const float* __restrict__ W,      // [E,32]
    const float* __restrict__ M1, const float* __restrict__ M2,
    const int* __restrict__ cnt, const int* __restrict__ off,
    const int* __restrict__ list,
    float* __restrict__ out,          // [N,3,32]
    int N)
{
    __shared__ float As[NVEC * NVEC];
    __shared__ float Bs[NVEC * NVEC];
    for (int i = threadIdx.x; i < NVEC * NVEC; i += blockDim.x) {
        float m1 = M1[i], m2 = M2[i];
        As[i] = 0.5f * (m1 + m2);
        Bs[i] = 0.5f * (m2 - m1);
    }
    __syncthreads();

    int wave = threadIdx.x >> 6;                 // 0..3
    int n = blockIdx.x * 4 + wave;
    if (n >= N) return;
    int lane = threadIdx.x & 63;
    int halfbase = lane & 32;                     // 0 (dst) or 32 (src)
    int l = lane & 31;

    int seg = halfbase ? (N + n) : n;
    int base = off[seg];
    int c = cnt[seg];

    float x0 = 0.f, x1 = 0.f, x2 = 0.f;          // per-lane sums, m=0..2

    for (int i0 = 0; i0 < c; i0 += 32) {
        int idx = i0 + l;
        int cl = idx < c ? idx : c - 1;
        int eidv = list[base + cl];               // cooperative 128B load
        int lim = c - i0; if (lim > 32) lim = 32;
        for (int j = 0; j < lim; ++j) {
            int e = __shfl(eidv, halfbase + j, 64);
            float w = W[(size_t)e * NVEC + l];
            const float* xr = xe + (size_t)e * ROW_F + l;
            x0 += w * xr[0];
            x1 += w * xr[32];
            x2 += w * xr[64];
        }
    }

    // mix: out[m][l] = sum_v x1[v]*A[v][l] + x2[v]*B[v][l]
    float o0 = 0.f, o1 = 0.f, o2 = 0.f;
    #pragma unroll
    for (int v = 0; v < NVEC; ++v) {
        float a = As[v * NVEC + l];
        float b = Bs[v * NVEC + l];
        o0 += __shfl(x0, v, 64) * a + __shfl(x0, 32 + v, 64) * b;
        o1 += __shfl(x1, v, 64) * a + __shfl(x1, 32 + v, 64) * b;
        o2 += __shfl(x2, v, 64) * a + __shfl(x2, 32 + v, 64) * b;
    }
    if (halfbase == 0) {
        float* orow = out + (size_t)n * ROW_F;
        orow[l]      = o0;
        orow[32 + l] = o1;
        orow[64 + l] = o2;
    }
}

extern "C" void kernel_launch(void* const* d_in, const int* in_sizes, int n_in,
                              void* d_out, int out_size, void* d_ws, size_t ws_size,
                              hipStream_t stream)
{
    const float* xe  = (const float*)d_in[0];
    const float* W   = (const float*)d_in[1];
    const float* M1  = (const float*)d_in[2];
    const float* M2  = (const float*)d_in[3];
    const int* xsrc  = (const int*)d_in[4];
    const int* xdst  = (const int*)d_in[5];

    const int E = in_sizes[4];
    const int N = out_size / ROW_F;
    const int nseg = 2 * N;

    int* wsi     = (int*)d_ws;
    int* counts  = wsi;
    int* offsets = wsi + nseg;
    int* cursors = wsi + 2 * nseg;
    int* list    = wsi + 3 * nseg;
    // ws need: (3*2N + 2E)*4 = 7.6 MB  (<= proven-available 19.2 MB)

    hipMemsetAsync(counts, 0, (size_t)nseg * sizeof(int), stream);

    const int eblocks = (E + 255) / 256;
    hist_kernel<<<eblocks, 256, 0, stream>>>(xdst, xsrc, counts, E, N);
    scan_kernel<<<1, 1024, 0, stream>>>(counts, offsets, cursors, nseg);
    scatter_kernel<<<eblocks, 256, 0, stream>>>(xdst, xsrc, cursors, list, E, N);

    const int nblocks = (N + 3) / 4;              // 4 nodes (waves) per block
    gather_mix_kernel<<<nblocks, 256, 0, stream>>>(
        xe, W, M1, M2, counts, offsets, list, (float*)d_out, N);
}

// Round 3
// 845.077 us; speedup vs baseline: 2.8565x; 1.4660x over previous
//
#include <hip/hip_runtime.h>

#define MID 3
#define NVEC 32
#define ROW_F 96   // MID*NVEC

// ---------------------------------------------------------------------------
// Device-built CSR over 2N segments: seg n   = edges with dst==n  (side 1)
//                                    seg N+n = edges with src==n  (side 2)
// ws layout (ints): counts[2N] | offsets[2N] | cursors[2N] | list[2E] | bsum[256]
// ---------------------------------------------------------------------------

__global__ __launch_bounds__(256) void hist_kernel(
    const int* __restrict__ dst, const int* __restrict__ src,
    int* __restrict__ cnt, int E, int N)
{
    int t = blockIdx.x * blockDim.x + threadIdx.x;
    if (t >= E) return;
    atomicAdd(&cnt[dst[t]], 1);
    atomicAdd(&cnt[N + src[t]], 1);
}

// --- parallel scan: A) per-block sums, B) scan of block sums, C) local scan+add
#define SCAN_TPB 256
#define SCAN_EPB 1024   // elems per block (4 per thread, int4)

__global__ __launch_bounds__(SCAN_TPB) void scanA_kernel(
    const int* __restrict__ cnt, int* __restrict__ bsum, int n)
{
    __shared__ int sdata[SCAN_TPB];
    int b = blockIdx.x, t = threadIdx.x;
    int i4 = b * SCAN_EPB + t * 4;
    int s = 0;
    if (i4 + 3 < n) {
        int4 v = *(const int4*)(cnt + i4);
        s = v.x + v.y + v.z + v.w;
    } else {
        for (int k = 0; k < 4; ++k) if (i4 + k < n) s += cnt[i4 + k];
    }
    sdata[t] = s;
    __syncthreads();
    for (int o = SCAN_TPB / 2; o > 0; o >>= 1) {
        if (t < o) sdata[t] += sdata[t + o];
        __syncthreads();
    }
    if (t == 0) bsum[b] = sdata[0];
}

__global__ __launch_bounds__(SCAN_TPB) void scanB_kernel(
    int* __restrict__ bsum, int nb)   // in-place exclusive scan, nb <= 256
{
    __shared__ int sdata[SCAN_TPB];
    int t = threadIdx.x;
    int v = (t < nb) ? bsum[t] : 0;
    sdata[t] = v;
    __syncthreads();
    for (int o = 1; o < SCAN_TPB; o <<= 1) {
        int u = (t >= o) ? sdata[t - o] : 0;
        __syncthreads();
        sdata[t] += u;
        __syncthreads();
    }
    if (t < nb) bsum[t] = sdata[t] - v;   // exclusive
}

__global__ __launch_bounds__(SCAN_TPB) void scanC_kernel(
    const int* __restrict__ cnt, const int* __restrict__ bsum,
    int* __restrict__ off, int* __restrict__ cur, int n)
{
    __shared__ int sdata[SCAN_TPB];
    int b = blockIdx.x, t = threadIdx.x;
    int i4 = b * SCAN_EPB + t * 4;
    int4 v = make_int4(0, 0, 0, 0);
    if (i4 + 3 < n) {
        v = *(const int4*)(cnt + i4);
    } else {
        if (i4 + 0 < n) v.x = cnt[i4 + 0];
        if (i4 + 1 < n) v.y = cnt[i4 + 1];
        if (i4 + 2 < n) v.z = cnt[i4 + 2];
    }
    int tot = v.x + v.y + v.z + v.w;
    sdata[t] = tot;
    __syncthreads();
    for (int o = 1; o < SCAN_TPB; o <<= 1) {
        int u = (t >= o) ? sdata[t - o] : 0;
        __syncthreads();
        sdata[t] += u;
        __syncthreads();
    }
    int run = bsum[b] + sdata[t] - tot;    // exclusive prefix of this thread's 4
    int4 o4;
    o4.x = run;
    o4.y = run + v.x;
    o4.z = run + v.x + v.y;
    o4.w = run + v.x + v.y + v.z;
    if (i4 + 3 < n) {
        *(int4*)(off + i4) = o4;
        *(int4*)(cur + i4) = o4;
    } else {
        if (i4 + 0 < n) { off[i4 + 0] = o4.x; cur[i4 + 0] = o4.x; }
        if (i4 + 1 < n) { off[i4 + 1] = o4.y; cur[i4 + 1] = o4.y; }
        if (i4 + 2 < n) { off[i4 + 2] = o4.z; cur[i4 + 2] = o4.z; }
    }
}

__global__ __launch_bounds__(256) void scatter_kernel(
    const int* __restrict__ dst, const int* __restrict__ src,
    int* __restrict__ cur, int* __restrict__ list, int E, int N)
{
    int t = blockIdx.x * blockDim.x + threadIdx.x;
    if (t >= E) return;
    int p = atomicAdd(&cur[dst[t]], 1);
    list[p] = t;
    int q = atomicAdd(&cur[N + src[t]], 1);
    list[q] = t;
}

// ---------------------------------------------------------------------------
// One 64-lane wave per node. Lanes 0-31: dst-edge sum (x1). Lanes 32-63:
// src-edge sum (x2). Edge loop unrolled x4: 16 independent loads in flight
// per half-wave before any use (MLP). Tail: clamp edge index, zero weight.
// Then fused mix out = x1@A + x2@B, A=0.5*(M1+M2), B=0.5*(M2-M1), via shfl.
// ---------------------------------------------------------------------------
__global__ __launch_bounds__(256) void gather_mix_kernel(
    const float* __restrict__ xe,     // [E,3,32]
    const float* __restrict__ W,      // [E,32]
    const float* __restrict__ M1, const float* __restrict__ M2,
    const int* __restrict__ cnt, const int* __restrict__ off,
    const int* __restrict__ list,
    float* __restrict__ out,          // [N,3,32]
    int N)
{
    __shared__ float As[NVEC * NVEC];
    __shared__ float Bs[NVEC * NVEC];
    for (int i = threadIdx.x; i < NVEC * NVEC; i += blockDim.x) {
        float m1 = M1[i], m2 = M2[i];
        As[i] = 0.5f * (m1 + m2);
        Bs[i] = 0.5f * (m2 - m1);
    }
    __syncthreads();

    int wave = threadIdx.x >> 6;                 // 0..3
    int n = blockIdx.x * 4 + wave;
    if (n >= N) return;
    int lane = threadIdx.x & 63;
    int halfbase = lane & 32;                     // 0 (dst-side) or 32 (src-side)
    int l = lane & 31;

    int seg = halfbase ? (N + n) : n;
    int base = off[seg];
    int c = cnt[seg];

    float acc0 = 0.f, acc1 = 0.f, acc2 = 0.f;

    for (int i0 = 0; i0 < c; i0 += 32) {
        int idx = i0 + l;
        int cl = idx < c ? idx : c - 1;
        int eidv = list[base + cl];               // cooperative chunk load
        int lim = c - i0; if (lim > 32) lim = 32;
        for (int j = 0; j < lim; j += 4) {
            int j1 = j + 1 < lim ? j + 1 : lim - 1;
            int j2 = j + 2 < lim ? j + 2 : lim - 1;
            int j3 = j + 3 < lim ? j + 3 : lim - 1;
            int e0 = __shfl(eidv, halfbase + j,  64);
            int e1 = __shfl(eidv, halfbase + j1, 64);
            int e2 = __shfl(eidv, halfbase + j2, 64);
            int e3 = __shfl(eidv, halfbase + j3, 64);

            float w0 = W[(size_t)e0 * NVEC + l];
            float w1 = W[(size_t)e1 * NVEC + l];
            float w2 = W[(size_t)e2 * NVEC + l];
            float w3 = W[(size_t)e3 * NVEC + l];
            if (j + 1 >= lim) w1 = 0.f;
            if (j + 2 >= lim) w2 = 0.f;
            if (j + 3 >= lim) w3 = 0.f;

            const float* x0p = xe + (size_t)e0 * ROW_F + l;
            const float* x1p = xe + (size_t)e1 * ROW_F + l;
            const float* x2p = xe + (size_t)e2 * ROW_F + l;
            const float* x3p = xe + (size_t)e3 * ROW_F + l;
            float a00 = x0p[0],  a10 = x1p[0],  a20 = x2p[0],  a30 = x3p[0];
            float a01 = x0p[32], a11 = x1p[32], a21 = x2p[32], a31 = x3p[32];
            float a02 = x0p[64], a12 = x1p[64], a22 = x2p[64], a32 = x3p[64];

            acc0 += w0 * a00 + w1 * a10 + w2 * a20 + w3 * a30;
            acc1 += w0 * a01 + w1 * a11 + w2 * a21 + w3 * a31;
            acc2 += w0 * a02 + w1 * a12 + w2 * a22 + w3 * a32;
        }
    }

    // mix: out[m][l] = sum_v x1[m][v]*A[v][l] + x2[m][v]*B[v][l]
    float o0 = 0.f, o1 = 0.f, o2 = 0.f;
    #pragma unroll
    for (int v = 0; v < NVEC; ++v) {
        float a = As[v * NVEC + l];
        float b = Bs[v * NVEC + l];
        o0 += __shfl(acc0, v, 64) * a + __shfl(acc0, 32 + v, 64) * b;
        o1 += __shfl(acc1, v, 64) * a + __shfl(acc1, 32 + v, 64) * b;
        o2 += __shfl(acc2, v, 64) * a + __shfl(acc2, 32 + v, 64) * b;
    }
    if (halfbase == 0) {
        float* orow = out + (size_t)n * ROW_F;
        orow[l]      = o0;
        orow[32 + l] = o1;
        orow[64 + l] = o2;
    }
}

extern "C" void kernel_launch(void* const* d_in, const int* in_sizes, int n_in,
                              void* d_out, int out_size, void* d_ws, size_t ws_size,
                              hipStream_t stream)
{
    const float* xe  = (const float*)d_in[0];
    const float* W   = (const float*)d_in[1];
    const float* M1  = (const float*)d_in[2];
    const float* M2  = (const float*)d_in[3];
    const int* xsrc  = (const int*)d_in[4];
    const int* xdst  = (const int*)d_in[5];

    const int E = in_sizes[4];
    const int N = out_size / ROW_F;
    const int nseg = 2 * N;

    int* wsi     = (int*)d_ws;
    int* counts  = wsi;
    int* offsets = wsi + nseg;
    int* cursors = wsi + 2 * nseg;
    int* list    = wsi + 3 * nseg;
    int* bsum    = wsi + 3 * nseg + 2 * E;
    // ws need: (3*2N + 2E + 256)*4 ~= 7.6 MB

    hipMemsetAsync(counts, 0, (size_t)nseg * sizeof(int), stream);

    const int eblocks = (E + 255) / 256;
    hist_kernel<<<eblocks, 256, 0, stream>>>(xdst, xsrc, counts, E, N);

    const int nscan = (nseg + SCAN_EPB - 1) / SCAN_EPB;   // <= 256 blocks
    scanA_kernel<<<nscan, SCAN_TPB, 0, stream>>>(counts, bsum, nseg);
    scanB_kernel<<<1, SCAN_TPB, 0, stream>>>(bsum, nscan);
    scanC_kernel<<<nscan, SCAN_TPB, 0, stream>>>(counts, bsum, offsets, cursors, nseg);

    scatter_kernel<<<eblocks, 256, 0, stream>>>(xdst, xsrc, cursors, list, E, N);

    const int nblocks = (N + 3) / 4;              // 4 nodes (waves) per block
    gather_mix_kernel<<<nblocks, 256, 0, stream>>>(
        xe, W, M1, M2, counts, offsets, list, (float*)d_out, N);
}